// Round 1
// baseline (250164.380 us; speedup 1.0000x reference)
//
#include <hip/hip_runtime.h>

#define T_N 512
#define B_N 32
#define IN_N 512
#define H_N 512
#define G3 1536
#define NBLK 256
#define NT 768
#define CPB 4          // hidden cols per block
#define GC 12          // gate-cols per block (3 gates x CPB)
#define LDW 516        // LDS row stride (512 + pad)
#define EPS_LN 1e-5f

#define OUT_HID_OFF (T_N * B_N * 1024)

__device__ __forceinline__ float dot512(const float* __restrict__ row,
                                        const float* __restrict__ wcol) {
  const float4* r4 = (const float4*)row;
  const float4* w4 = (const float4*)wcol;
  float a0 = 0.f, a1 = 0.f, a2 = 0.f, a3 = 0.f;
#pragma unroll 8
  for (int i = 0; i < 128; ++i) {
    float4 a = r4[i];
    float4 w = w4[i];
    a0 += a.x * w.x;
    a1 += a.y * w.y;
    a2 += a.z * w.z;
    a3 += a.w * w.w;
  }
  return (a0 + a1) + (a2 + a3);
}

__device__ __forceinline__ void gbar(unsigned* bar, unsigned& epoch) {
  epoch++;
  __threadfence();          // release my writes (agent scope)
  __syncthreads();          // whole block fenced + arrived
  if (threadIdx.x == 0) {
    __hip_atomic_fetch_add(bar, 1u, __ATOMIC_RELAXED, __HIP_MEMORY_SCOPE_AGENT);
    const unsigned target = epoch * NBLK;
    while (__hip_atomic_load(bar, __ATOMIC_RELAXED, __HIP_MEMORY_SCOPE_AGENT) < target) {
      __builtin_amdgcn_s_sleep(2);
    }
  }
  __syncthreads();
  __threadfence();          // acquire: see others' writes
}

__global__ void __launch_bounds__(NT, 1)
lngru_coop(const float* __restrict__ x, const float* __restrict__ h0,
           const float* __restrict__ Wx, const float* __restrict__ Wh,
           const float* __restrict__ bx, const float* __restrict__ bh,
           const float* __restrict__ gx, const float* __restrict__ bex,
           const float* __restrict__ gh, const float* __restrict__ beh,
           float* __restrict__ out, float* __restrict__ ws)
{
  __shared__ __align__(16) float wxl[GC * LDW];
  __shared__ __align__(16) float whl[GC * LDW];
  __shared__ float dots[NT];

  unsigned* bar = (unsigned*)ws;
  float* stats = ws + 64;                 // [2 parity][2 d][2 kind][32 b][3 g][2]
  float* hbuf  = ws + 64 + 1536;          // [2 d][32 b][512]
  float* y0    = hbuf + 2 * B_N * H_N;    // [2 d][512 t][32 b][512]

  const int tid = threadIdx.x;
  const int bid = blockIdx.x;
  const int d   = bid >> 7;       // layer-dir within phase: 0 fwd, 1 bwd
  const int cb  = bid & 127;      // column-block
  const int c0  = cb * CPB;       // hidden-col base

  unsigned epoch = 0;

  // prologue: init this block's h slice for phase 0 (stats+bar zeroed by memset)
  if (tid < 128) {
    int cl = tid >> 5, b = tid & 31;
    hbuf[(d * B_N + b) * H_N + c0 + cl] = h0[(d * B_N + b) * H_N + c0 + cl];
  }
  gbar(bar, epoch);

  for (int ph = 0; ph < 2; ++ph) {
    const int widx = ph * 2 + d;

    // stage weight column slices into LDS: w[cg][k], k-contiguous
    for (int idx = tid; idx < IN_N * GC; idx += NT) {
      int k = idx / GC, cg = idx % GC;
      int J = (cg >> 2) * H_N + c0 + (cg & 3);
      wxl[cg * LDW + k] = Wx[(widx * IN_N + k) * G3 + J];
      whl[cg * LDW + k] = Wh[(widx * H_N + k) * G3 + J];
    }
    __syncthreads();

    const float* xbase = (ph == 0) ? x : (y0 + (size_t)d * T_N * B_N * H_N);

    for (int s = 0; s < T_N; ++s) {
      const int t = d ? (T_N - 1 - s) : s;
      const int p = s & 1;
      float* stp = stats + p * 768;

      // ---- phase 1: GEMM (one 512-dot per thread) ----
      {
        int kindcg = tid >> 5;            // 0..23
        int b = tid & 31;
        int kind = kindcg / GC;           // 0: ax, 1: ah
        int cg = kindcg % GC;
        int J = (cg >> 2) * H_N + c0 + (cg & 3);
        const float* row = kind ? (hbuf + (d * B_N + b) * H_N)
                                : (xbase + ((size_t)t * B_N + b) * IN_N);
        const float* wcol = (kind ? whl : wxl) + cg * LDW;
        float acc = dot512(row, wcol);
        acc += (kind ? bh : bx)[widx * G3 + J];
        dots[tid] = acc;
      }
      __syncthreads();

      // ---- LN stat partials -> global atomics ----
      if (tid < 192) {
        int kind = tid / 96, rem = tid % 96;
        int g = rem >> 5, b = rem & 31;
        float s1 = 0.f, s2 = 0.f;
#pragma unroll
        for (int w = 0; w < CPB; ++w) {
          float v = dots[(kind * GC + g * CPB + w) * B_N + b];
          s1 += v; s2 += v * v;
        }
        float* sl = stp + (((d * 2 + kind) * B_N + b) * 3 + g) * 2;
        atomicAdd(sl, s1);
        atomicAdd(sl + 1, s2);
      }
      gbar(bar, epoch);   // S1: stats complete

      // ---- phase 2: gates + h update ----
      if (bid == 0) {
        float* so = stats + (p ^ 1) * 768;   // zero other parity for step s+1
        if (tid < 768) so[tid] = 0.f;
      }
      if (tid < 128) {
        int cl = tid >> 5, b = tid & 31;
        int c = c0 + cl;
        float a[2][3];
#pragma unroll
        for (int kind = 0; kind < 2; ++kind) {
#pragma unroll
          for (int g = 0; g < 3; ++g) {
            float v = dots[(kind * GC + g * CPB + cl) * B_N + b];
            const float* sl = stp + (((d * 2 + kind) * B_N + b) * 3 + g) * 2;
            float mu  = sl[0] * (1.f / 512.f);
            float var = sl[1] * (1.f / 512.f) - mu * mu;
            float inv = rsqrtf(var + EPS_LN);
            int J = g * H_N + c;
            const float* gam = kind ? gh : gx;
            const float* bet = kind ? beh : bex;
            a[kind][g] = (v - mu) * inv * gam[widx * G3 + J] + bet[widx * G3 + J];
          }
        }
        float r = 1.f / (1.f + __expf(-(a[0][0] + a[1][0])));
        float z = 1.f / (1.f + __expf(-(a[0][1] + a[1][1])));
        float n = tanhf(a[0][2] + r * a[1][2]);
        float* hp = hbuf + (d * B_N + b) * H_N + c;
        float hnew = (1.f - z) * n + z * (*hp);
        *hp = hnew;
        if (ph == 0) {
          y0[(((size_t)d * T_N + t) * B_N + b) * H_N + c] = hnew;
        } else {
          out[((size_t)t * B_N + b) * 1024 + d * H_N + c] = hnew;
        }
        if (s == T_N - 1) {
          out[OUT_HID_OFF + ((ph * 2 + d) * B_N + b) * H_N + c] = hnew;
        }
      }
      gbar(bar, epoch);   // S2: h published
    }

    if (ph == 0) {
      // transition: init h slice for layer 1 (stats ring self-cleans)
      if (tid < 128) {
        int cl = tid >> 5, b = tid & 31;
        hbuf[(d * B_N + b) * H_N + c0 + cl] = h0[((2 + d) * B_N + b) * H_N + c0 + cl];
      }
      gbar(bar, epoch);
    }
  }
}

extern "C" void kernel_launch(void* const* d_in, const int* in_sizes, int n_in,
                              void* d_out, int out_size, void* d_ws, size_t ws_size,
                              hipStream_t stream) {
  const float* x   = (const float*)d_in[0];
  const float* h0  = (const float*)d_in[1];
  const float* Wx  = (const float*)d_in[2];
  const float* Wh  = (const float*)d_in[3];
  const float* bx  = (const float*)d_in[4];
  const float* bh  = (const float*)d_in[5];
  const float* gx  = (const float*)d_in[6];
  const float* bex = (const float*)d_in[7];
  const float* gh  = (const float*)d_in[8];
  const float* beh = (const float*)d_in[9];
  float* out = (float*)d_out;
  float* ws  = (float*)d_ws;

  // zero barrier counter + stats ring (graph-capture-legal)
  hipMemsetAsync(d_ws, 0, 8192, stream);

  void* args[] = {(void*)&x, (void*)&h0, (void*)&Wx, (void*)&Wh, (void*)&bx, (void*)&bh,
                  (void*)&gx, (void*)&bex, (void*)&gh, (void*)&beh, (void*)&out, (void*)&ws};
  hipLaunchCooperativeKernel((void*)lngru_coop, dim3(NBLK), dim3(NT), args, 0, stream);
}

// Round 2
// 195477.942 us; speedup vs baseline: 1.2798x; 1.2798x over previous
//
#include <hip/hip_runtime.h>

#define T_N 512
#define B_N 32
#define H_N 512
#define G3 1536
#define NBLK 192
#define NT 1024
#define EPS_LN 1e-5f
#define OUT_HID_OFF (T_N * B_N * 1024)

// ws layout (floats):
//  [0]       barrier counter (u32), [32] release (u32)
//  [64]      stats ring: 2 parity x (4 kd x 3 g x 32 b x 2) = 2 x 768
//  [1600]    dots: 4 kd x 32 b x 1536 j                      = 196608
//  [198208]  hbuf: 2 d x 32 b x 512                          = 32768
//  [230976]  y0: 2 d x 512 t x 32 b x 512                    = 16777216
#define WS_STATS 64
#define WS_DOTS  (WS_STATS + 1536)
#define WS_HBUF  (WS_DOTS + 4 * B_N * G3)
#define WS_Y0    (WS_HBUF + 2 * B_N * H_N)

__device__ __forceinline__ void gbar(unsigned* bar, unsigned* rel, unsigned& epoch) {
  epoch++;
  __threadfence();
  __syncthreads();
  if (threadIdx.x == 0) {
    unsigned r = __hip_atomic_fetch_add(bar, 1u, __ATOMIC_RELAXED, __HIP_MEMORY_SCOPE_AGENT);
    if (r == epoch * NBLK - 1u) {
      __hip_atomic_store(rel, epoch, __ATOMIC_RELAXED, __HIP_MEMORY_SCOPE_AGENT);
    } else {
      while (__hip_atomic_load(rel, __ATOMIC_RELAXED, __HIP_MEMORY_SCOPE_AGENT) < epoch)
        __builtin_amdgcn_s_sleep(1);
    }
  }
  __syncthreads();
  __threadfence();
}

__global__ void __launch_bounds__(NT, 4)
lngru2(const float* __restrict__ x, const float* __restrict__ h0,
       const float* __restrict__ Wx, const float* __restrict__ Wh,
       const float* __restrict__ bx, const float* __restrict__ bh,
       const float* __restrict__ gx, const float* __restrict__ bex,
       const float* __restrict__ gh, const float* __restrict__ beh,
       float* __restrict__ out, float* __restrict__ ws)
{
  // [wave][bb][lane] k-partial exchange: 16*16*64*4 = 64 KB
  __shared__ float red[16 * 16 * 64];

  unsigned* bar = (unsigned*)ws;
  unsigned* rel = (unsigned*)ws + 32;
  float* stats = ws + WS_STATS;
  float* dots  = ws + WS_DOTS;
  float* hbuf  = ws + WS_HBUF;
  float* y0    = ws + WS_Y0;

  const int tid  = threadIdx.x;
  const int lane = tid & 63;
  const int wv   = __builtin_amdgcn_readfirstlane(tid >> 6);  // 0..15, k-split & b-owner
  const int bid  = blockIdx.x;
  const int bs   = bid & 1;
  const int jt   = (bid >> 1) % 24;       // 64-wide j tile
  const int kd   = (bid >> 1) / 24;       // d*2 + kind
  const int kind = kd & 1;                // 0: ax, 1: ah
  const int d    = kd >> 1;
  const int j0   = jt * 64;
  const int g    = jt >> 3;               // gate of this j-tile
  const int b0   = bs * 16;
  const bool is_gate = (kind == 0) && (jt < 8);
  const int k0 = wv * 32;

  unsigned epoch = 0;

  for (int ph = 0; ph < 2; ++ph) {
    const int widx = ph * 2 + d;

    // init h for this phase (gate blocks own the (d,c,b) partition)
    if (is_gate) {
      hbuf[(d * B_N + b0 + wv) * H_N + j0 + lane] =
          h0[((ph * 2 + d) * B_N + b0 + wv) * H_N + j0 + lane];
    }
    gbar(bar, rel, epoch);

    const float* wbase = (kind ? Wh : Wx) + (size_t)widx * H_N * G3;
    const float* wc    = wbase + j0 + lane;                  // + k*G3 per row
    const float  bv    = (kind ? bh : bx)[widx * G3 + j0 + lane];
    const float* xsrc  = (ph == 0) ? x : (y0 + (size_t)d * T_N * B_N * H_N);
    const float* hrow  = hbuf + (d * B_N + b0) * H_N;        // [16][512]

    for (int s = 0; s < T_N; ++s) {
      const int t = d ? (T_N - 1 - s) : s;
      const int p = s & 1;
      float* stp = stats + p * 768;

      // ---- GEMM: 64 j (lanes) x 16 b (regs) x 32 k (this wave) ----
      const float* rp = kind ? hrow : (xsrc + (size_t)t * B_N * H_N + b0 * H_N);
      float acc[16];
#pragma unroll
      for (int bb = 0; bb < 16; ++bb) acc[bb] = 0.f;

#pragma unroll
      for (int kq = 0; kq < 8; ++kq) {
        float w0 = wc[(k0 + kq * 4 + 0) * G3];
        float w1 = wc[(k0 + kq * 4 + 1) * G3];
        float w2 = wc[(k0 + kq * 4 + 2) * G3];
        float w3 = wc[(k0 + kq * 4 + 3) * G3];
#pragma unroll
        for (int bb = 0; bb < 16; ++bb) {
          float4 r4 = *(const float4*)(rp + bb * H_N + k0 + kq * 4);
          acc[bb] = fmaf(r4.x, w0, acc[bb]);
          acc[bb] = fmaf(r4.y, w1, acc[bb]);
          acc[bb] = fmaf(r4.z, w2, acc[bb]);
          acc[bb] = fmaf(r4.w, w3, acc[bb]);
        }
      }

      // ---- k-reduction across the 16 waves via LDS ----
#pragma unroll
      for (int bb = 0; bb < 16; ++bb) red[(wv * 16 + bb) * 64 + lane] = acc[bb];
      __syncthreads();
      // wave wv owns b = b0+wv: sum its column across all 16 k-slices
      float tot = bv;
#pragma unroll
      for (int w2 = 0; w2 < 16; ++w2) tot += red[(w2 * 16 + wv) * 64 + lane];

      // publish dot (coalesced 64 lanes)
      dots[(kd * B_N + b0 + wv) * G3 + j0 + lane] = tot;

      // LN stat partials: butterfly over 64 j, one atomic pair per wave
      float s1 = tot, s2 = tot * tot;
#pragma unroll
      for (int m = 32; m > 0; m >>= 1) {
        s1 += __shfl_xor(s1, m, 64);
        s2 += __shfl_xor(s2, m, 64);
      }
      if (lane == 0) {
        float* sl = stp + ((kd * 3 + g) * B_N + b0 + wv) * 2;
        atomicAdd(sl, s1);
        atomicAdd(sl + 1, s2);
      }

      gbar(bar, rel, epoch);  // B1: all dots + stats complete

      // ---- gates + h update (gate blocks) ----
      if (bid == NBLK - 1) {
        float* so = stats + (p ^ 1) * 768;   // clean other parity for next step
        if (tid < 768) so[tid] = 0.f;
      }
      if (is_gate) {
        const int c = j0 + lane;
        const int b = b0 + wv;
        float a[2][3];
#pragma unroll
        for (int k2 = 0; k2 < 2; ++k2) {
          const float* dr = dots + ((d * 2 + k2) * B_N + b) * G3;
          const float* gam = (k2 ? gh : gx) + widx * G3;
          const float* bet = (k2 ? beh : bex) + widx * G3;
#pragma unroll
          for (int g2 = 0; g2 < 3; ++g2) {
            float v = dr[g2 * H_N + c];
            const float* sl = stp + (((d * 2 + k2) * 3 + g2) * B_N + b) * 2;
            float mu  = sl[0] * (1.f / 512.f);
            float var = sl[1] * (1.f / 512.f) - mu * mu;
            float inv = rsqrtf(var + EPS_LN);
            int J = g2 * H_N + c;
            a[k2][g2] = (v - mu) * inv * gam[J] + bet[J];
          }
        }
        float r = 1.f / (1.f + __expf(-(a[0][0] + a[1][0])));
        float z = 1.f / (1.f + __expf(-(a[0][1] + a[1][1])));
        float n = tanhf(a[0][2] + r * a[1][2]);
        float* hp = hbuf + (d * B_N + b) * H_N + c;
        float hnew = (1.f - z) * n + z * (*hp);
        *hp = hnew;
        if (ph == 0) {
          y0[(((size_t)d * T_N + t) * B_N + b) * H_N + c] = hnew;
        } else {
          out[((size_t)t * B_N + b) * 1024 + d * H_N + c] = hnew;
        }
        if (s == T_N - 1) {
          out[OUT_HID_OFF + ((ph * 2 + d) * B_N + b) * H_N + c] = hnew;
        }
      }
      gbar(bar, rel, epoch);  // B2: h published
    }
  }
}

extern "C" void kernel_launch(void* const* d_in, const int* in_sizes, int n_in,
                              void* d_out, int out_size, void* d_ws, size_t ws_size,
                              hipStream_t stream) {
  const float* x   = (const float*)d_in[0];
  const float* h0  = (const float*)d_in[1];
  const float* Wx  = (const float*)d_in[2];
  const float* Wh  = (const float*)d_in[3];
  const float* bx  = (const float*)d_in[4];
  const float* bh  = (const float*)d_in[5];
  const float* gx  = (const float*)d_in[6];
  const float* bex = (const float*)d_in[7];
  const float* gh  = (const float*)d_in[8];
  const float* beh = (const float*)d_in[9];
  float* out = (float*)d_out;
  float* ws  = (float*)d_ws;

  // zero barrier counter + release + both stat parities
  hipMemsetAsync(d_ws, 0, (WS_STATS + 1536) * sizeof(float), stream);

  void* args[] = {(void*)&x, (void*)&h0, (void*)&Wx, (void*)&Wh, (void*)&bx, (void*)&bh,
                  (void*)&gx, (void*)&bex, (void*)&gh, (void*)&beh, (void*)&out, (void*)&ws};
  hipLaunchCooperativeKernel((void*)lngru2, dim3(NBLK), dim3(NT), args, 0, stream);
}

// Round 3
// 40621.091 us; speedup vs baseline: 6.1585x; 4.8122x over previous
//
#include <hip/hip_runtime.h>

#define T_N 512
#define B_N 32
#define H_N 512
#define G3 1536
#define NBLK 192
#define NT 1024
#define EPS_LN 1e-5f
#define OUT_HID_OFF (T_N * B_N * 1024)

// ws layout (floats):
//  [0]  barrier counter (u32), [32] release flag (u32)
//  [64]      stats ring: 2 parity x (4 kd x 3 g x 32 b x 2) = 2 x 768
//  [1600]    dots: 4 kd x 32 b x 1536 j
//  [198208]  hbuf: 2 d x 32 b x 512
//  [230976]  y0: 2 d x 512 t x 32 b x 512
#define WS_STATS 64
#define WS_DOTS  (WS_STATS + 1536)
#define WS_HBUF  (WS_DOTS + 4 * B_N * G3)
#define WS_Y0    (WS_HBUF + 2 * B_N * H_N)

// Coherent (L3-point) access: relaxed agent-scope atomics compile to
// global_load/store with sc0+sc1 -- bypass L1/L2, no wbl2/inv cache
// maintenance ever. ALL ws traffic uses these (harness poison-memset and
// write-around stores make plain cached reads of ws unsafe).
__device__ __forceinline__ float cload(const float* p) {
  return __hip_atomic_load(p, __ATOMIC_RELAXED, __HIP_MEMORY_SCOPE_AGENT);
}
__device__ __forceinline__ void cstore(float* p, float v) {
  __hip_atomic_store(p, v, __ATOMIC_RELAXED, __HIP_MEMORY_SCOPE_AGENT);
}

// Fence-free grid barrier: drain own vmem (coherent stores retire at L3 =
// device coherence point), arrive on relaxed counter, poll relaxed flag.
__device__ __forceinline__ void gbar(unsigned* bar, unsigned* rel, unsigned& epoch) {
  epoch++;
  __builtin_amdgcn_s_waitcnt(0);   // vmcnt(0) lgkmcnt(0): my stores are globally visible
  __syncthreads();                 // whole block arrived + drained
  if (threadIdx.x == 0) {
    unsigned r = __hip_atomic_fetch_add(bar, 1u, __ATOMIC_RELAXED, __HIP_MEMORY_SCOPE_AGENT);
    if (r == epoch * NBLK - 1u) {
      __hip_atomic_store(rel, epoch, __ATOMIC_RELAXED, __HIP_MEMORY_SCOPE_AGENT);
    } else {
      while (__hip_atomic_load(rel, __ATOMIC_RELAXED, __HIP_MEMORY_SCOPE_AGENT) < epoch)
        __builtin_amdgcn_s_sleep(2);
    }
  }
  __syncthreads();
}

template <bool COH>
__device__ __forceinline__ void gemm16(const float* __restrict__ rp,
                                       const float* __restrict__ wc,
                                       int k0, float* __restrict__ acc) {
#pragma unroll
  for (int kq = 0; kq < 8; ++kq) {
    float w0 = wc[(k0 + kq * 4 + 0) * G3];
    float w1 = wc[(k0 + kq * 4 + 1) * G3];
    float w2 = wc[(k0 + kq * 4 + 2) * G3];
    float w3 = wc[(k0 + kq * 4 + 3) * G3];
#pragma unroll
    for (int bb = 0; bb < 16; ++bb) {
      const float* r = rp + bb * H_N + k0 + kq * 4;
      float rx, ry, rz, rw;
      if (COH) {
        rx = cload(r + 0); ry = cload(r + 1); rz = cload(r + 2); rw = cload(r + 3);
      } else {
        float4 q = *(const float4*)r;
        rx = q.x; ry = q.y; rz = q.z; rw = q.w;
      }
      acc[bb] = fmaf(rx, w0, acc[bb]);
      acc[bb] = fmaf(ry, w1, acc[bb]);
      acc[bb] = fmaf(rz, w2, acc[bb]);
      acc[bb] = fmaf(rw, w3, acc[bb]);
    }
  }
}

__global__ void __launch_bounds__(NT, 4)
lngru3(const float* __restrict__ x, const float* __restrict__ h0,
       const float* __restrict__ Wx, const float* __restrict__ Wh,
       const float* __restrict__ bx, const float* __restrict__ bh,
       const float* __restrict__ gx, const float* __restrict__ bex,
       const float* __restrict__ gh, const float* __restrict__ beh,
       float* __restrict__ out, float* __restrict__ ws)
{
  __shared__ float red[16 * 16 * 64];   // [wave][bb][lane] k-partial exchange

  unsigned* bar = (unsigned*)ws;
  unsigned* rel = (unsigned*)ws + 32;
  float* stats = ws + WS_STATS;
  float* dots  = ws + WS_DOTS;
  float* hbuf  = ws + WS_HBUF;
  float* y0    = ws + WS_Y0;

  const int tid  = threadIdx.x;
  const int lane = tid & 63;
  const int wv   = __builtin_amdgcn_readfirstlane(tid >> 6);  // 0..15
  const int bid  = blockIdx.x;
  const int bs   = bid & 1;
  const int jt   = (bid >> 1) % 24;       // 64-wide j tile
  const int kd   = (bid >> 1) / 24;       // d*2 + kind
  const int kind = kd & 1;                // 0: ax, 1: ah
  const int d    = kd >> 1;
  const int j0   = jt * 64;
  const int g    = jt >> 3;               // gate of this j-tile
  const int b0   = bs * 16;
  const bool is_gate = (kind == 0) && (jt < 8);
  const int k0 = wv * 32;

  unsigned epoch = 0;

  for (int ph = 0; ph < 2; ++ph) {
    const int widx = ph * 2 + d;

    if (is_gate) {
      cstore(&hbuf[(d * B_N + b0 + wv) * H_N + j0 + lane],
             h0[((ph * 2 + d) * B_N + b0 + wv) * H_N + j0 + lane]);
    }
    gbar(bar, rel, epoch);

    const float* wbase = (kind ? Wh : Wx) + (size_t)widx * H_N * G3;
    const float* wc    = wbase + j0 + lane;
    const float  bv    = (kind ? bh : bx)[widx * G3 + j0 + lane];
    const float* xsrc  = (ph == 0) ? x : (y0 + (size_t)d * T_N * B_N * H_N);
    const float* hrow  = hbuf + (d * B_N + b0) * H_N;
    const bool coh_rows = (kind == 1) || (ph == 1);  // h always; y0 in ph1

    for (int s = 0; s < T_N; ++s) {
      const int t = d ? (T_N - 1 - s) : s;
      const int p = s & 1;
      float* stp = stats + p * 768;

      // ---- GEMM: 64 j (lanes) x 16 b (regs) x 32 k (this wave) ----
      const float* rp = kind ? hrow : (xsrc + (size_t)t * B_N * H_N + b0 * H_N);
      float acc[16];
#pragma unroll
      for (int bb = 0; bb < 16; ++bb) acc[bb] = 0.f;
      if (coh_rows) gemm16<true>(rp, wc, k0, acc);
      else          gemm16<false>(rp, wc, k0, acc);

      // ---- k-reduction across the 16 waves via LDS ----
#pragma unroll
      for (int bb = 0; bb < 16; ++bb) red[(wv * 16 + bb) * 64 + lane] = acc[bb];
      __syncthreads();
      float tot = bv;
#pragma unroll
      for (int w2 = 0; w2 < 16; ++w2) tot += red[(w2 * 16 + wv) * 64 + lane];

      cstore(&dots[(kd * B_N + b0 + wv) * G3 + j0 + lane], tot);

      // LN stat partials: butterfly over 64 j, one atomic pair per wave
      float s1 = tot, s2 = tot * tot;
#pragma unroll
      for (int m = 32; m > 0; m >>= 1) {
        s1 += __shfl_xor(s1, m, 64);
        s2 += __shfl_xor(s2, m, 64);
      }
      if (lane == 0) {
        float* sl = stp + ((kd * 3 + g) * B_N + b0 + wv) * 2;
        atomicAdd(sl, s1);
        atomicAdd(sl + 1, s2);
      }

      gbar(bar, rel, epoch);  // B1: all dots + stats visible

      // ---- gates + h update ----
      if (bid == NBLK - 1) {
        float* so = stats + (p ^ 1) * 768;
        if (tid < 768) cstore(so + tid, 0.f);
      }
      if (is_gate) {
        const int c = j0 + lane;
        const int b = b0 + wv;
        float a[2][3];
#pragma unroll
        for (int k2 = 0; k2 < 2; ++k2) {
          const float* dr = dots + ((d * 2 + k2) * B_N + b) * G3;
          const float* gam = (k2 ? gh : gx) + widx * G3;
          const float* bet = (k2 ? beh : bex) + widx * G3;
#pragma unroll
          for (int g2 = 0; g2 < 3; ++g2) {
            float v = cload(dr + g2 * H_N + c);
            const float* sl = stp + (((d * 2 + k2) * 3 + g2) * B_N + b) * 2;
            float mu  = cload(sl)     * (1.f / 512.f);
            float var = cload(sl + 1) * (1.f / 512.f) - mu * mu;
            float inv = rsqrtf(var + EPS_LN);
            int J = g2 * H_N + c;
            a[k2][g2] = (v - mu) * inv * gam[J] + bet[J];
          }
        }
        float r = 1.f / (1.f + __expf(-(a[0][0] + a[1][0])));
        float z = 1.f / (1.f + __expf(-(a[0][1] + a[1][1])));
        float n = tanhf(a[0][2] + r * a[1][2]);
        float* hp = hbuf + (d * B_N + b) * H_N + c;
        float hnew = (1.f - z) * n + z * cload(hp);
        cstore(hp, hnew);
        if (ph == 0) {
          cstore(&y0[(((size_t)d * T_N + t) * B_N + b) * H_N + c], hnew);
        } else {
          out[((size_t)t * B_N + b) * 1024 + d * H_N + c] = hnew;
        }
        if (s == T_N - 1) {
          out[OUT_HID_OFF + ((ph * 2 + d) * B_N + b) * H_N + c] = hnew;
        }
      }
      gbar(bar, rel, epoch);  // B2: h(t) visible
    }
  }
}

extern "C" void kernel_launch(void* const* d_in, const int* in_sizes, int n_in,
                              void* d_out, int out_size, void* d_ws, size_t ws_size,
                              hipStream_t stream) {
  const float* x   = (const float*)d_in[0];
  const float* h0  = (const float*)d_in[1];
  const float* Wx  = (const float*)d_in[2];
  const float* Wh  = (const float*)d_in[3];
  const float* bx  = (const float*)d_in[4];
  const float* bh  = (const float*)d_in[5];
  const float* gx  = (const float*)d_in[6];
  const float* bex = (const float*)d_in[7];
  const float* gh  = (const float*)d_in[8];
  const float* beh = (const float*)d_in[9];
  float* out = (float*)d_out;
  float* ws  = (float*)d_ws;

  // zero barrier counter + release + both stat parities
  hipMemsetAsync(d_ws, 0, 8192, stream);

  void* args[] = {(void*)&x, (void*)&h0, (void*)&Wx, (void*)&Wh, (void*)&bx, (void*)&bh,
                  (void*)&gx, (void*)&bex, (void*)&gh, (void*)&beh, (void*)&out, (void*)&ws};
  hipLaunchCooperativeKernel((void*)lngru3, dim3(NBLK), dim3(NT), args, 0, stream);
}

// Round 4
// 37805.161 us; speedup vs baseline: 6.6172x; 1.0745x over previous
//
#include <hip/hip_runtime.h>

#define T_N 512
#define B_N 32
#define H_N 512
#define G3 1536
#define NBLK 192
#define NT 1024
#define EPS_LN 1e-5f
#define OUT_HID_OFF (T_N * B_N * 1024)

// ws layout (floats):
//  [0] barrier counter, [32] release flag
//  [64]      stats ring: 2 parity x (4 kd x 3 g x 32 b x 2) = 2 x 768
//  [1600]    dots: 4 kd x 32 b x 1536 j
//  [198208]  hbuf: 2 d x 32 b x 512
//  [230976]  y0: 2 d x 512 t x 32 b x 512   (write-once in ph0 -> plain-read ph1)
#define WS_STATS 64
#define WS_DOTS  (WS_STATS + 1536)
#define WS_HBUF  (WS_DOTS + 4 * B_N * G3)
#define WS_Y0    (WS_HBUF + 2 * B_N * H_N)

// Coherent L3-point access (sc0 sc1, no cache maintenance). All mutable
// cross-block state (dots/stats/hbuf/bar) goes through these.
__device__ __forceinline__ float cload(const float* p) {
  return __hip_atomic_load(p, __ATOMIC_RELAXED, __HIP_MEMORY_SCOPE_AGENT);
}
__device__ __forceinline__ void cstore(float* p, float v) {
  __hip_atomic_store(p, v, __ATOMIC_RELAXED, __HIP_MEMORY_SCOPE_AGENT);
}
union U64F2 { unsigned long long u; float f[2]; };
__device__ __forceinline__ U64F2 cload2(const float* p) {
  U64F2 r;
  r.u = __hip_atomic_load((const unsigned long long*)p, __ATOMIC_RELAXED,
                          __HIP_MEMORY_SCOPE_AGENT);
  return r;
}

// Fence-free grid barrier (validated round 3).
__device__ __forceinline__ void gbar(unsigned* bar, unsigned* rel, unsigned& epoch) {
  epoch++;
  __builtin_amdgcn_s_waitcnt(0);   // drain my vmem: coherent stores are at L3
  __syncthreads();
  if (threadIdx.x == 0) {
    unsigned r = __hip_atomic_fetch_add(bar, 1u, __ATOMIC_RELAXED, __HIP_MEMORY_SCOPE_AGENT);
    if (r == epoch * NBLK - 1u) {
      __hip_atomic_store(rel, epoch, __ATOMIC_RELAXED, __HIP_MEMORY_SCOPE_AGENT);
    } else {
      while (__hip_atomic_load(rel, __ATOMIC_RELAXED, __HIP_MEMORY_SCOPE_AGENT) < epoch)
        __builtin_amdgcn_s_sleep(2);
    }
  }
  __syncthreads();
}

__global__ void __launch_bounds__(NT, 4)
lngru4(const float* __restrict__ x, const float* __restrict__ h0,
       const float* __restrict__ Wx, const float* __restrict__ Wh,
       const float* __restrict__ bx, const float* __restrict__ bh,
       const float* __restrict__ gx, const float* __restrict__ bex,
       const float* __restrict__ gh, const float* __restrict__ beh,
       float* __restrict__ out, float* __restrict__ ws)
{
  extern __shared__ __align__(16) float smem[];
  float* wlds = smem;            // 32768 floats: [k4 128][j 64][4] = 64j x 512k W slice
  float* sred = smem + 32768;    // 256 floats: [wave 16][boct 8][2]

  unsigned* bar = (unsigned*)ws;
  unsigned* rel = (unsigned*)ws + 32;
  float* stats = ws + WS_STATS;
  float* dots  = ws + WS_DOTS;
  float* hbuf  = ws + WS_HBUF;
  float* y0    = ws + WS_Y0;

  const int tid  = threadIdx.x;
  const int lane = tid & 63;
  const int wv   = tid >> 6;              // 16 waves
  const int bid  = blockIdx.x;
  const int bs   = bid & 1;               // b-half
  const int jt   = (bid >> 1) % 24;       // 64-wide j tile
  const int kd   = (bid >> 1) / 24;       // d*2 + kind
  const int kind = kd & 1;                // 0: ax, 1: ah
  const int d    = kd >> 1;
  const int j0   = jt * 64;
  const int g    = jt >> 3;               // gate of this j-tile
  const int b0   = bs * 16;
  const bool is_gate = (kind == 0) && (jt < 8);

  // GEMM decomposition: wave = (jq 8) x (bhf 2); lane = (boct 8)x(jj 8).
  const int jq    = wv >> 1;
  const int bhf   = wv & 1;
  const int jj    = lane & 7;
  const int boct  = lane >> 3;
  const int b_loc = bhf * 8 + boct;       // 0..15 within block's b-half
  const int b     = b0 + b_loc;
  const int jfull = j0 + jq * 8 + jj;     // 0..1535

  unsigned epoch = 0;

  for (int ph = 0; ph < 2; ++ph) {
    const int widx = ph * 2 + d;

    // ---- stage 64j x 512k weight slice into LDS (once per phase) ----
    {
      const float* wgl = (kind ? Wh : Wx) + (size_t)widx * H_N * G3 + j0;
      for (int kk = 0; kk < 32; ++kk) {
        int k = wv * 32 + kk;
        float v = wgl[(size_t)k * G3 + lane];          // coalesced 64-float row
        wlds[(k >> 2) * 256 + lane * 4 + (k & 3)] = v; // [k4][j][kc]
      }
    }
    // init h for this phase (gate blocks own the (d,c,b-half) partition)
    if (is_gate) {
      cstore(&hbuf[(d * B_N + b0 + wv) * H_N + j0 + lane],
             h0[(widx * B_N + b0 + wv) * H_N + j0 + lane]);
    }
    gbar(bar, rel, epoch);

    const float  bv   = (kind ? bh : bx)[widx * G3 + jfull];
    const float* xsrc = (ph == 0) ? x : (y0 + (size_t)d * T_N * B_N * H_N);
    const float* hrow = hbuf + (d * B_N + b) * H_N;
    const float4* wq  = (const float4*)wlds + jq * 8 + jj;   // + k4*64

    for (int s = 0; s < T_N; ++s) {
      const int t = d ? (T_N - 1 - s) : s;
      const int p = s & 1;
      float* stp = stats + p * 768;

      // ---- GEMM: this lane computes dot for (jfull, b), full K=512 ----
      const float* rp = kind ? hrow : (xsrc + ((size_t)t * B_N + b) * H_N);
      float p0 = 0.f, p1 = 0.f, p2 = 0.f, p3 = 0.f;
      if (kind) {
#pragma unroll 8
        for (int k4 = 0; k4 < 128; ++k4) {
          float4 w = wq[k4 * 64];
          U64F2 h01 = cload2(rp + k4 * 4);
          U64F2 h23 = cload2(rp + k4 * 4 + 2);
          p0 = fmaf(h01.f[0], w.x, p0);
          p1 = fmaf(h01.f[1], w.y, p1);
          p2 = fmaf(h23.f[0], w.z, p2);
          p3 = fmaf(h23.f[1], w.w, p3);
        }
      } else {
#pragma unroll 8
        for (int k4 = 0; k4 < 128; ++k4) {
          float4 w = wq[k4 * 64];
          float4 r = *(const float4*)(rp + k4 * 4);
          p0 = fmaf(r.x, w.x, p0);
          p1 = fmaf(r.y, w.y, p1);
          p2 = fmaf(r.z, w.z, p2);
          p3 = fmaf(r.w, w.w, p3);
        }
      }
      float tot = bv + (p0 + p1) + (p2 + p3);

      cstore(&dots[(kd * B_N + b) * G3 + jfull], tot);

      // ---- LN stats: butterfly over 8 jj lanes, per-wave stage in LDS ----
      float s1 = tot, s2 = tot * tot;
      s1 += __shfl_xor(s1, 1, 64); s2 += __shfl_xor(s2, 1, 64);
      s1 += __shfl_xor(s1, 2, 64); s2 += __shfl_xor(s2, 2, 64);
      s1 += __shfl_xor(s1, 4, 64); s2 += __shfl_xor(s2, 4, 64);
      if (jj == 0) {
        sred[(wv * 8 + boct) * 2 + 0] = s1;
        sred[(wv * 8 + boct) * 2 + 1] = s2;
      }
      __syncthreads();
      if (tid < 32) {
        int bl = tid >> 1, st = tid & 1;
        int bh2 = bl >> 3, bo2 = bl & 7;
        float a2 = 0.f;
#pragma unroll
        for (int q = 0; q < 8; ++q) a2 += sred[((q * 2 + bh2) * 8 + bo2) * 2 + st];
        atomicAdd(&stp[((kd * 3 + g) * B_N + b0 + bl) * 2 + st], a2);
      }

      gbar(bar, rel, epoch);  // B1: dots + stats visible

      // ---- gates + h update ----
      if (bid == NBLK - 1) {
        float* so = stats + (p ^ 1) * 768;
        if (tid < 768) cstore(so + tid, 0.f);
      }
      if (is_gate) {
        const int c  = j0 + lane;
        const int gb = b0 + wv;
        float a[2][3];
#pragma unroll
        for (int k2 = 0; k2 < 2; ++k2) {
          const float* dr  = dots + ((d * 2 + k2) * B_N + gb) * G3;
          const float* gam = (k2 ? gh : gx) + widx * G3;
          const float* bet = (k2 ? beh : bex) + widx * G3;
#pragma unroll
          for (int g2 = 0; g2 < 3; ++g2) {
            float v = cload(dr + g2 * H_N + c);
            const float* sl = stp + (((d * 2 + k2) * 3 + g2) * B_N + gb) * 2;
            float mu  = cload(sl)     * (1.f / 512.f);
            float var = cload(sl + 1) * (1.f / 512.f) - mu * mu;
            float inv = rsqrtf(var + EPS_LN);
            int J = g2 * H_N + c;
            a[k2][g2] = (v - mu) * inv * gam[J] + bet[J];
          }
        }
        float r = 1.f / (1.f + __expf(-(a[0][0] + a[1][0])));
        float z = 1.f / (1.f + __expf(-(a[0][1] + a[1][1])));
        float n = tanhf(a[0][2] + r * a[1][2]);
        float* hp = hbuf + (d * B_N + gb) * H_N + c;
        float hnew = (1.f - z) * n + z * cload(hp);
        cstore(hp, hnew);
        if (ph == 0) {
          cstore(&y0[(((size_t)d * T_N + t) * B_N + gb) * H_N + c], hnew);
        } else {
          out[((size_t)t * B_N + gb) * 1024 + d * H_N + c] = hnew;
        }
        if (s == T_N - 1) {
          out[OUT_HID_OFF + (widx * B_N + gb) * H_N + c] = hnew;
        }
      }
      gbar(bar, rel, epoch);  // B2: h(t) visible
    }
  }
}

extern "C" void kernel_launch(void* const* d_in, const int* in_sizes, int n_in,
                              void* d_out, int out_size, void* d_ws, size_t ws_size,
                              hipStream_t stream) {
  const float* x    = (const float*)d_in[0];
  const float* h0   = (const float*)d_in[1];
  const float* Wx   = (const float*)d_in[2];
  const float* Wh   = (const float*)d_in[3];
  const float* bxp  = (const float*)d_in[4];
  const float* bhp  = (const float*)d_in[5];
  const float* gxp  = (const float*)d_in[6];
  const float* bexp = (const float*)d_in[7];
  const float* ghp  = (const float*)d_in[8];
  const float* behp = (const float*)d_in[9];
  float* out = (float*)d_out;
  float* ws  = (float*)d_ws;

  hipMemsetAsync(d_ws, 0, 8192, stream);

  const int kDynLds = (32768 + 256) * 4;   // 132 KB: weights + stats scratch
  hipFuncSetAttribute((const void*)lngru4,
                      hipFuncAttributeMaxDynamicSharedMemorySize, kDynLds);

  void* args[] = {(void*)&x, (void*)&h0, (void*)&Wx, (void*)&Wh, (void*)&bxp, (void*)&bhp,
                  (void*)&gxp, (void*)&bexp, (void*)&ghp, (void*)&behp, (void*)&out, (void*)&ws};
  hipLaunchCooperativeKernel((void*)lngru4, dim3(NBLK), dim3(NT), args, kDynLds, stream);
}

// Round 5
// 26062.991 us; speedup vs baseline: 9.5985x; 1.4505x over previous
//
#include <hip/hip_runtime.h>

#define T_N 512
#define B_N 32
#define H_N 512
#define G3 1536
#define NBLK 192
#define NGRP 8
#define GRPSZ (NBLK / NGRP)     // 24
#define NT 1024
#define EPS_LN 1e-5f
#define OUT_HID_OFF (T_N * B_N * 1024)

// ws layout (floats):
//  [0..320)     barrier: 8 group counters (32-float spacing) + top + release
//  [320]        stats ring: 2 parity x (4 kd x 3 g x 32 b x 2) = 2 x 768
//  [1856]       dots: 4 kd x 32 b x 1536 j
//  [198464]     hbuf: 2 d x 32 b x 512
//  [231232]     y0: 2 d x 512 t x 32 b x 512  (cstore ph0, plain-read ph1)
#define WS_STATS 320
#define WS_DOTS  (WS_STATS + 1536)
#define WS_HBUF  (WS_DOTS + 4 * B_N * G3)
#define WS_Y0    (WS_HBUF + 2 * B_N * H_N)

// LDS (dynamic, 163072 B total):
//  wlds: 126 k4 x 64 j x 4  = 32256 floats (k = 0..503)
//  hl:   16 b x 516         =  8256 floats (k-padded h tile)
//  sred: 256 floats
#define WLDS_F 32256
#define HL_F   8256
#define LDS_BYTES ((WLDS_F + HL_F + 256) * 4)

__device__ __forceinline__ float cload(const float* p) {
  return __hip_atomic_load(p, __ATOMIC_RELAXED, __HIP_MEMORY_SCOPE_AGENT);
}
__device__ __forceinline__ void cstore(float* p, float v) {
  __hip_atomic_store(p, v, __ATOMIC_RELAXED, __HIP_MEMORY_SCOPE_AGENT);
}
union U64F2 { unsigned long long u; float f[2]; };
__device__ __forceinline__ U64F2 cload2(const float* p) {
  U64F2 r;
  r.u = __hip_atomic_load((const unsigned long long*)p, __ATOMIC_RELAXED,
                          __HIP_MEMORY_SCOPE_AGENT);
  return r;
}

// Hierarchical fence-free grid barrier: 24-way arrive on 8 separate lines,
// 8-way top, single release flag. (Round-4 flat version: 192 serialized
// same-line RMWs ~ 14 us; this cuts serialization ~8x.)
__device__ __forceinline__ void gbar(unsigned* barbase, unsigned& epoch, int grp) {
  epoch++;
  __builtin_amdgcn_s_waitcnt(0);   // drain my vmem: coherent stores at L3
  __syncthreads();
  if (threadIdx.x == 0) {
    unsigned* gc  = barbase + grp * 32;
    unsigned* top = barbase + NGRP * 32;
    unsigned* rel = barbase + NGRP * 32 + 32;
    unsigned r = __hip_atomic_fetch_add(gc, 1u, __ATOMIC_RELAXED, __HIP_MEMORY_SCOPE_AGENT);
    if (r == epoch * GRPSZ - 1u) {
      unsigned r2 = __hip_atomic_fetch_add(top, 1u, __ATOMIC_RELAXED, __HIP_MEMORY_SCOPE_AGENT);
      if (r2 == epoch * NGRP - 1u)
        __hip_atomic_store(rel, epoch, __ATOMIC_RELAXED, __HIP_MEMORY_SCOPE_AGENT);
    }
    while (__hip_atomic_load(rel, __ATOMIC_RELAXED, __HIP_MEMORY_SCOPE_AGENT) < epoch)
      __builtin_amdgcn_s_sleep(1);
  }
  __syncthreads();
}

__global__ void __launch_bounds__(NT, 1)
lngru5(const float* __restrict__ x, const float* __restrict__ h0,
       const float* __restrict__ Wx, const float* __restrict__ Wh,
       const float* __restrict__ bx, const float* __restrict__ bh,
       const float* __restrict__ gx, const float* __restrict__ bex,
       const float* __restrict__ gh, const float* __restrict__ beh,
       float* __restrict__ out, float* __restrict__ ws)
{
  extern __shared__ __align__(16) float smem[];
  float* wlds = smem;                    // [k4 126][j 64][4]
  float* hl   = smem + WLDS_F;           // [b 16][516]
  float* sred = smem + WLDS_F + HL_F;    // [wave 16][boct 8][2]

  unsigned* barbase = (unsigned*)ws;
  float* stats = ws + WS_STATS;
  float* dots  = ws + WS_DOTS;
  float* hbuf  = ws + WS_HBUF;
  float* y0    = ws + WS_Y0;

  const int tid  = threadIdx.x;
  const int lane = tid & 63;
  const int wv   = tid >> 6;              // 16 waves
  const int bid  = blockIdx.x;
  const int grp  = bid & 7;
  const int bs   = bid & 1;               // b-half
  const int jt   = (bid >> 1) % 24;       // 64-wide j tile
  const int kd   = (bid >> 1) / 24;       // d*2 + kind
  const int kind = kd & 1;                // 0: ax, 1: ah
  const int d    = kd >> 1;
  const int j0   = jt * 64;
  const int g    = jt >> 3;               // gate of this j-tile
  const int b0   = bs * 16;
  const bool is_gate = (kind == 0) && (jt < 8);

  // GEMM decomposition: wave = (jq 8) x (bhf 2); lane = (boct 8)x(jj 8).
  const int jq    = wv >> 1;
  const int bhf   = wv & 1;
  const int jj    = lane & 7;
  const int boct  = lane >> 3;
  const int b_loc = bhf * 8 + boct;       // 0..15 in block's b-half
  const int b     = b0 + b_loc;
  const int jfull = j0 + jq * 8 + jj;

  unsigned epoch = 0;

  for (int ph = 0; ph < 2; ++ph) {
    const int widx = ph * 2 + d;

    // ---- stage weights: k<504 -> LDS, k>=504 -> per-lane regs ----
    const float* wgl = (kind ? Wh : Wx) + (size_t)widx * H_N * G3 + j0;
    for (int kk = 0; kk < 32; ++kk) {
      int k = wv * 32 + kk;
      if (k < 504)
        wlds[(k >> 2) * 256 + lane * 4 + (k & 3)] = wgl[(size_t)k * G3 + lane];
    }
    float wtail[8];
#pragma unroll
    for (int kk = 0; kk < 8; ++kk)
      wtail[kk] = wgl[(size_t)(504 + kk) * G3 + (jq * 8 + jj)];

    if (is_gate) {
      cstore(&hbuf[(d * B_N + b0 + wv) * H_N + j0 + lane],
             h0[(widx * B_N + b0 + wv) * H_N + j0 + lane]);
    }
    gbar(barbase, epoch, grp);

    const float  bv   = (kind ? bh : bx)[widx * G3 + jfull];
    const float* xsrc = (ph == 0) ? x : (y0 + (size_t)d * T_N * B_N * H_N);
    const float* hsrc = hbuf + (d * B_N + b0) * H_N;   // 16 b x 512, contiguous
    const float4* wq  = (const float4*)wlds + jq * 8 + jj;

    for (int s = 0; s < T_N; ++s) {
      const int t = d ? (T_N - 1 - s) : s;
      const int p = s & 1;
      float* stp = stats + p * 768;

      // ---- kind=1: stage h(t-1) tile into LDS (coalesced coherent) ----
      if (kind) {
#pragma unroll
        for (int q = 0; q < 4; ++q) {
          int e = (tid + q * 1024) * 2;       // element 0..8190, even
          U64F2 v = cload2(hsrc + e);
          int bb = e >> 9, k = e & 511;
          hl[bb * 516 + k]     = v.f[0];
          hl[bb * 516 + k + 1] = v.f[1];
        }
        __syncthreads();
      }

      // ---- GEMM: lane computes dot(jfull, b), K=512 ----
      float p0 = 0.f, p1 = 0.f, p2 = 0.f, p3 = 0.f;
      if (kind) {
        const float* hb = hl + b_loc * 516;
#pragma unroll 9
        for (int k4 = 0; k4 < 126; ++k4) {
          float4 w = wq[k4 * 64];
          float4 r = *(const float4*)(hb + k4 * 4);
          p0 = fmaf(r.x, w.x, p0);
          p1 = fmaf(r.y, w.y, p1);
          p2 = fmaf(r.z, w.z, p2);
          p3 = fmaf(r.w, w.w, p3);
        }
        float4 r1 = *(const float4*)(hb + 504);
        float4 r2 = *(const float4*)(hb + 508);
        p0 = fmaf(r1.x, wtail[0], p0); p1 = fmaf(r1.y, wtail[1], p1);
        p2 = fmaf(r1.z, wtail[2], p2); p3 = fmaf(r1.w, wtail[3], p3);
        p0 = fmaf(r2.x, wtail[4], p0); p1 = fmaf(r2.y, wtail[5], p1);
        p2 = fmaf(r2.z, wtail[6], p2); p3 = fmaf(r2.w, wtail[7], p3);
      } else {
        const float* rp = xsrc + ((size_t)t * B_N + b) * H_N;
#pragma unroll 9
        for (int k4 = 0; k4 < 126; ++k4) {
          float4 w = wq[k4 * 64];
          float4 r = *(const float4*)(rp + k4 * 4);
          p0 = fmaf(r.x, w.x, p0);
          p1 = fmaf(r.y, w.y, p1);
          p2 = fmaf(r.z, w.z, p2);
          p3 = fmaf(r.w, w.w, p3);
        }
        float4 r1 = *(const float4*)(rp + 504);
        float4 r2 = *(const float4*)(rp + 508);
        p0 = fmaf(r1.x, wtail[0], p0); p1 = fmaf(r1.y, wtail[1], p1);
        p2 = fmaf(r1.z, wtail[2], p2); p3 = fmaf(r1.w, wtail[3], p3);
        p0 = fmaf(r2.x, wtail[4], p0); p1 = fmaf(r2.y, wtail[5], p1);
        p2 = fmaf(r2.z, wtail[6], p2); p3 = fmaf(r2.w, wtail[7], p3);
      }
      float tot = bv + (p0 + p1) + (p2 + p3);

      cstore(&dots[(kd * B_N + b) * G3 + jfull], tot);

      // ---- LN stats: jj-butterfly, per-wave LDS stage, 32-lane atomics ----
      float s1 = tot, s2 = tot * tot;
      s1 += __shfl_xor(s1, 1, 64); s2 += __shfl_xor(s2, 1, 64);
      s1 += __shfl_xor(s1, 2, 64); s2 += __shfl_xor(s2, 2, 64);
      s1 += __shfl_xor(s1, 4, 64); s2 += __shfl_xor(s2, 4, 64);
      if (jj == 0) {
        sred[(wv * 8 + boct) * 2 + 0] = s1;
        sred[(wv * 8 + boct) * 2 + 1] = s2;
      }
      __syncthreads();
      if (tid < 32) {
        int bl = tid >> 1, st = tid & 1;
        int bh2 = bl >> 3, bo2 = bl & 7;
        float a2 = 0.f;
#pragma unroll
        for (int q = 0; q < 8; ++q) a2 += sred[((q * 2 + bh2) * 8 + bo2) * 2 + st];
        atomicAdd(&stp[((kd * 3 + g) * B_N + b0 + bl) * 2 + st], a2);
      }

      gbar(barbase, epoch, grp);  // B1: dots + stats visible

      // ---- gates + h update ----
      if (bid == NBLK - 1) {
        float* so = stats + (p ^ 1) * 768;
        if (tid < 768) cstore(so + tid, 0.f);
      }
      if (is_gate) {
        const int c  = j0 + lane;
        const int gb = b0 + wv;
        float a[2][3];
#pragma unroll
        for (int k2 = 0; k2 < 2; ++k2) {
          const float* dr  = dots + ((d * 2 + k2) * B_N + gb) * G3;
          const float* gam = (k2 ? gh : gx) + widx * G3;
          const float* bet = (k2 ? beh : bex) + widx * G3;
#pragma unroll
          for (int g2 = 0; g2 < 3; ++g2) {
            float v = cload(dr + g2 * H_N + c);
            const float* sl = stp + (((d * 2 + k2) * 3 + g2) * B_N + gb) * 2;
            float mu  = cload(sl)     * (1.f / 512.f);
            float var = cload(sl + 1) * (1.f / 512.f) - mu * mu;
            float inv = rsqrtf(var + EPS_LN);
            int J = g2 * H_N + c;
            a[k2][g2] = (v - mu) * inv * gam[J] + bet[J];
          }
        }
        float r = 1.f / (1.f + __expf(-(a[0][0] + a[1][0])));
        float z = 1.f / (1.f + __expf(-(a[0][1] + a[1][1])));
        float n = tanhf(a[0][2] + r * a[1][2]);
        float* hp = hbuf + (d * B_N + gb) * H_N + c;
        float hnew = (1.f - z) * n + z * cload(hp);
        cstore(hp, hnew);
        if (ph == 0) {
          cstore(&y0[(((size_t)d * T_N + t) * B_N + gb) * H_N + c], hnew);
        } else {
          out[((size_t)t * B_N + gb) * 1024 + d * H_N + c] = hnew;
        }
        if (s == T_N - 1) {
          out[OUT_HID_OFF + (widx * B_N + gb) * H_N + c] = hnew;
        }
      }
      gbar(barbase, epoch, grp);  // B2: h(t) visible
    }
  }
}

extern "C" void kernel_launch(void* const* d_in, const int* in_sizes, int n_in,
                              void* d_out, int out_size, void* d_ws, size_t ws_size,
                              hipStream_t stream) {
  const float* x    = (const float*)d_in[0];
  const float* h0   = (const float*)d_in[1];
  const float* Wx   = (const float*)d_in[2];
  const float* Wh   = (const float*)d_in[3];
  const float* bxp  = (const float*)d_in[4];
  const float* bhp  = (const float*)d_in[5];
  const float* gxp  = (const float*)d_in[6];
  const float* bexp = (const float*)d_in[7];
  const float* ghp  = (const float*)d_in[8];
  const float* behp = (const float*)d_in[9];
  float* out = (float*)d_out;
  float* ws  = (float*)d_ws;

  hipMemsetAsync(d_ws, 0, 8192, stream);   // barrier lines + stats ring

  hipFuncSetAttribute((const void*)lngru5,
                      hipFuncAttributeMaxDynamicSharedMemorySize, LDS_BYTES);

  void* args[] = {(void*)&x, (void*)&h0, (void*)&Wx, (void*)&Wh, (void*)&bxp, (void*)&bhp,
                  (void*)&gxp, (void*)&bexp, (void*)&ghp, (void*)&behp, (void*)&out, (void*)&ws};
  hipLaunchCooperativeKernel((void*)lngru5, dim3(NBLK), dim3(NT), args, LDS_BYTES, stream);
}